// Round 9
// baseline (415.402 us; speedup 1.0000x reference)
//
#include <hip/hip_runtime.h>

typedef unsigned short u16;
typedef __attribute__((ext_vector_type(8))) short short8;    // 8 x bf16 (4 VGPRs)
typedef __attribute__((ext_vector_type(4))) float f32x4;     // 16x16 MFMA C/D
typedef __attribute__((ext_vector_type(16))) float f32x16;   // 32x32 MFMA C/D

#define DEVI __device__ __forceinline__

DEVI float u2f(u16 u) {
    unsigned int x = ((unsigned int)u) << 16;
    float f; __builtin_memcpy(&f, &x, 4); return f;
}
DEVI u16 f2u(float f) {  // RNE bf16 (finite values)
    unsigned int x; __builtin_memcpy(&x, &f, 4);
    x = (x + 0x7fffu + ((x >> 16) & 1u)) >> 16;
    return (u16)x;
}
DEVI unsigned int fbits(float f) {
    unsigned int x; __builtin_memcpy(&x, &f, 4); return x;
}
// pack two f32 (as truncated bf16) into one u32: [lo | hi<<16]
DEVI unsigned int pkbf(float lo, float hi) {
    return __builtin_amdgcn_perm(fbits(hi), fbits(lo), 0x07060302u);
}
// async global->LDS, 16B per lane; lds base must be wave-uniform (m104/m108)
DEVI void gld16(const u16* g, u16* ldsbase) {
    __builtin_amdgcn_global_load_lds(
        (const __attribute__((address_space(1))) unsigned int*)g,
        (__attribute__((address_space(3))) unsigned int*)ldsbase, 16, 0, 0);
}

// ---------------------------------------------------------------------------
// Prep (one launch): blocks 0..4095 convert x fp32->bf16 (8 floats/thread);
// blocks 4096..6655 transpose the four weight matrices to K-inner bf16.
// grid 6656, block 256.
__global__ __launch_bounds__(256) void prep(
    const float* __restrict__ x,
    const float* __restrict__ Wq, const float* __restrict__ Wk,
    const float* __restrict__ Wv, const float* __restrict__ Wo,
    u16* __restrict__ xbf, u16* __restrict__ WTqkv, u16* __restrict__ WoT)
{
    __shared__ u16 T[64 * 72];
    int id = blockIdx.x;
    const int tid = threadIdx.x;
    if (id < 4096) {
        int g = (id * 256 + tid) * 8;
        float4 a = *(const float4*)&x[g];
        float4 c = *(const float4*)&x[g + 4];
        short8 v;
        v[0]=(short)f2u(a.x); v[1]=(short)f2u(a.y); v[2]=(short)f2u(a.z); v[3]=(short)f2u(a.w);
        v[4]=(short)f2u(c.x); v[5]=(short)f2u(c.y); v[6]=(short)f2u(c.z); v[7]=(short)f2u(c.w);
        *(short8*)&xbf[g] = v;
        return;
    }
    id -= 4096;
    const float* W; u16* WT; int N, bx, by;
    if (id < 1024)      {            W = Wo; WT = WoT;   N = 2048; bx = id & 31; by = id >> 5; }
    else if (id < 2048) { id -= 1024; W = Wq; WT = WTqkv; N = 2048; bx = id & 31; by = id >> 5; }
    else if (id < 2304) { id -= 2048; W = Wk; WT = WTqkv + (size_t)2048 * 2048; N = 512; bx = id & 7; by = id >> 3; }
    else                { id -= 2304; W = Wv; WT = WTqkv + (size_t)2560 * 2048; N = 512; bx = id & 7; by = id >> 3; }
    const int K = 2048;
    const int k0 = by * 64, n0 = bx * 64;
#pragma unroll
    for (int i = 0; i < 2; ++i) {
        int c = tid + i * 256;              // 0..511
        int row = c >> 3, n8 = (c & 7) * 8;
        const float* src = &W[(size_t)(k0 + row) * N + n0 + n8];
#pragma unroll
        for (int j = 0; j < 8; ++j)
            T[(n8 + j) * 72 + row] = f2u(src[j]);
    }
    __syncthreads();
#pragma unroll
    for (int i = 0; i < 2; ++i) {
        int c = tid + i * 256;
        int n = c >> 3, k8 = (c & 7) * 8;
        *(short8*)&WT[(size_t)(n0 + n) * K + k0 + k8] = *(const short8*)&T[n * 72 + k8];
    }
}

// ---------------------------------------------------------------------------
// GEMM: C[M][N] = A[M][K] @ WT[N][K]^T (+ optional fp32 residual).
// m97 structure: unpadded [128][32] LDS tiles, global_load_lds width=16.
// If fuse_norm: N-tiles with n0<2560 get per-head RMSNorm fused in epilogue.
// C written fp32 if c_f32 else bf16.  grid (N/128, M/128), block 256.
__global__ __launch_bounds__(256) void gemm_lds(
    const u16* __restrict__ A, int lda,
    const u16* __restrict__ WT,
    void* __restrict__ C, int ldc, const float* __restrict__ resid, int c_f32,
    int M, int N, int K,
    const float* __restrict__ qg, const float* __restrict__ kg, int fuse_norm)
{
    __shared__ u16 As[128 * 32];
    __shared__ u16 Bs[128 * 32];
    const int tid = threadIdx.x;
    const int lane = tid & 63, w = tid >> 6;
    const int wm = w >> 1, wn = w & 1;
    const int l15 = lane & 15, quad = lane >> 4;
    const int r4 = lane >> 2, c4 = (lane & 3) * 8;  // DMA: lane->row/col-8
    const int m0 = blockIdx.y * 128, n0 = blockIdx.x * 128;

    f32x4 acc[4][4] = {};
    for (int k0 = 0; k0 < K; k0 += 32) {
#pragma unroll
        for (int j = 0; j < 2; ++j) {
            int row = w * 32 + j * 16;
            gld16(&WT[(size_t)(n0 + row + r4) * K + k0 + c4], &Bs[row * 32]);
            gld16(&A [(size_t)(m0 + row + r4) * lda + k0 + c4], &As[row * 32]);
        }
        __syncthreads();
        short8 a[4], b[4];
#pragma unroll
        for (int mt = 0; mt < 4; ++mt)
            a[mt] = *(const short8*)&As[(wm * 64 + mt * 16 + l15) * 32 + quad * 8];
#pragma unroll
        for (int nt = 0; nt < 4; ++nt)
            b[nt] = *(const short8*)&Bs[(wn * 64 + nt * 16 + l15) * 32 + quad * 8];
#pragma unroll
        for (int mt = 0; mt < 4; ++mt)
#pragma unroll
            for (int nt = 0; nt < 4; ++nt)
                acc[mt][nt] = __builtin_amdgcn_mfma_f32_16x16x32_bf16(a[mt], b[nt], acc[mt][nt], 0, 0, 0);
        __syncthreads();
    }

    if (fuse_norm && n0 < 2560) {
        const float* gamma = (n0 < 2048) ? qg : kg;
        float* red = (float*)As;             // 256 floats, As is dead
#pragma unroll
        for (int mt = 0; mt < 4; ++mt)
#pragma unroll
            for (int r = 0; r < 4; ++r) {
                float p = 0.f;
#pragma unroll
                for (int nt = 0; nt < 4; ++nt) p += acc[mt][nt][r] * acc[mt][nt][r];
#pragma unroll
                for (int msk = 1; msk < 16; msk <<= 1) p += __shfl_xor(p, msk);
                if (l15 == 0)
                    red[(wm * 64 + mt * 16 + quad * 4 + r) * 2 + wn] = p;
            }
        __syncthreads();
        float gv[4];
#pragma unroll
        for (int nt = 0; nt < 4; ++nt) gv[nt] = gamma[wn * 64 + nt * 16 + l15];
#pragma unroll
        for (int mt = 0; mt < 4; ++mt)
#pragma unroll
            for (int r = 0; r < 4; ++r) {
                int rl = wm * 64 + mt * 16 + quad * 4 + r;
                float m2 = red[rl * 2] + red[rl * 2 + 1];
                float sc = rsqrtf(m2 * (1.0f / 128.0f) + 1e-8f);
#pragma unroll
                for (int nt = 0; nt < 4; ++nt) acc[mt][nt][r] *= sc * gv[nt];
            }
    }

#pragma unroll
    for (int mt = 0; mt < 4; ++mt) {
#pragma unroll
        for (int r = 0; r < 4; ++r) {
            int row = m0 + wm * 64 + mt * 16 + quad * 4 + r;
#pragma unroll
            for (int nt = 0; nt < 4; ++nt) {
                int col = n0 + wn * 64 + nt * 16 + l15;
                float v = acc[mt][nt][r];
                if (resid) v += resid[(size_t)row * ldc + col];
                if (c_f32) ((float*)C)[(size_t)row * ldc + col] = v;
                else       ((u16*)C)[(size_t)row * ldc + col] = f2u(v);
            }
        }
    }
}

// ---------------------------------------------------------------------------
// V transpose: vT[(b*4+kvh)*128 + d][s] = qkv[(b*2048+s)][2560 + kvh*128 + d]
// grid (32, 4, 2), block 256.  (bf16)
__global__ __launch_bounds__(256) void vtrans(
    const u16* __restrict__ qkv, u16* __restrict__ vT)
{
    __shared__ u16 T[128 * 72];
    const int tid = threadIdx.x;
    const int t0 = blockIdx.x * 64;
    const int kvh = blockIdx.y, b = blockIdx.z;
#pragma unroll
    for (int i = 0; i < 4; ++i) {
        int c = tid + i * 256;                // 0..1023
        int tl = c >> 4, d8 = (c & 15) * 8;
        short8 v = *(const short8*)&qkv[(size_t)(b * 2048 + t0 + tl) * 3072 + 2560 + kvh * 128 + d8];
#pragma unroll
        for (int j = 0; j < 8; ++j)
            T[(d8 + j) * 72 + tl] = (u16)v[j];
    }
    __syncthreads();
#pragma unroll
    for (int i = 0; i < 4; ++i) {
        int c = tid + i * 256;
        int d = c >> 3, t8 = (c & 7) * 8;
        *(short8*)&vT[((size_t)(b * 4 + kvh) * 128 + d) * 2048 + t0 + t8] =
            *(const short8*)&T[d * 72 + t8];
    }
}

// ---------------------------------------------------------------------------
// Flash attention, causal, GQA, paired q-tiles (qt, 31-qt) => uniform 33
// kv-tiles/block, 4 waves/block.  ROUND 9: 32x32x16 MFMA.
// Diagnosis: r0/r6/r8 (3 structures) all pin at 106-107us with
// MfmaUtil+VALU ~38% -- the invariant is LDS issue traffic: each wave
// covering 16 q-rows reads the FULL 16KB K and V tiles (32 ds_read_b128)
// plus ~28 shuffle ops.  Fix: 32 q-rows per wave via mfma_32x32x16 (same
// 32 reads now serve 2x output), P half-exchange via 2 shfl_xor(32) per
// 16-kv chunk (8/iter, replaces 16-bpermute net), Q in registers (no Q
// LDS), defer-max (THR=8) makes the per-reg alpha broadcast rare.
// LDS ops per 32 q-rows: ~128 -> ~48.
// Layouts (32x32x16 bf16): A row=lane&31, k=(lane>>5)*8+e; B col=lane&31,
// k=(lane>>5)*8+e; C/D col=lane&31, row=(reg&3)+8*(reg>>2)+4*(lane>>5)
// [m74/m101-verified].  QK^T: A=K,B=Q => S^T[kv][q], lane q=l31 holds 16
// kv rows per 32-block (halves split rows mod 8: h2=0 {0-3,8-11,...}).
// PV: A=P^T (row=q=l31 -- lane-local!), B=V from vT rows => O[q][d],
// d=lane&31, q=reg-mapped.  Wave w: tile w>>1, q-half w&1.
// grid (16, 16, 2), block 256, LDS 32KB (K 64x256B + V 128x128B swizzled).
#define SWZ(row, coloff) ((coloff) ^ (((row) & 7) << 4))
__global__ __launch_bounds__(256) void attn(
    u16* __restrict__ qkv, const u16* __restrict__ vT)
{
    __shared__ u16 lds[16384];               // 32,768 B
    char* const Kb = (char*)lds;             // K: [64] rows x 256B, swizzled
    char* const Vb = (char*)lds + 16384;     // V: [128] rows x 128B, swizzled

    const int tid = threadIdx.x, lane = tid & 63, w = tid >> 6;
    const int t = w >> 1, half = w & 1;      // tile owner, q-half (32 rows)
    const int l31 = lane & 31, h2 = lane >> 5;
    const int h = blockIdx.y, b = blockIdx.z;
    const int kvh = h >> 2;
    const int qts[2] = { (int)blockIdx.x, 31 - (int)blockIdx.x };
    const int qt = qts[t];                   // this wave's q-tile
    const float scale = 0.08838834764831845f;

    // Q fragments direct global->reg (one-time): B-frag col q=l31 (own row),
    // k = ks*16 + h2*8 + e  => u16 offset ks*16 + h2*8
    short8 qf[8];
    {
        const u16* Qg = &qkv[(size_t)(b * 2048 + qt * 64 + half * 32 + l31) * 3072 + h * 128 + h2 * 8];
#pragma unroll
        for (int ks = 0; ks < 8; ++ks)
            qf[ks] = *(const short8*)&Qg[ks * 16];
    }

    f32x16 o2[4] = {};                       // O: 4 d-blocks of 32
    float m_ = -1e30f, l_ = 0.f;

    for (int kt = 0; kt <= qts[1]; ++kt) {
        const int kv0 = kt * 64;
        // stage K,V swizzled (256 threads: 4+4 b128 chunks/thread)
#pragma unroll
        for (int i = 0; i < 4; ++i) {
            int c = tid + i * 256;           // 0..1023
            int r = c >> 4, co = (c & 15) * 16;
            short8 v = *(const short8*)&qkv[(size_t)(b * 2048 + kv0 + r) * 3072 + 2048 + kvh * 128 + (c & 15) * 8];
            *(short8*)(Kb + r * 256 + SWZ(r, co)) = v;
        }
#pragma unroll
        for (int i = 0; i < 4; ++i) {
            int c = tid + i * 256;
            int d = c >> 3, co = (c & 7) * 16;
            short8 v = *(const short8*)&vT[((size_t)(b * 4 + kvh) * 128 + d) * 2048 + kv0 + (c & 7) * 8];
            *(short8*)(Vb + d * 128 + SWZ(d, co)) = v;
        }
        __syncthreads();

        if (kt <= qt) {                      // wave-uniform: tile active
            // S^T = K Q^T : two 32x32 tiles over kv
            f32x16 s2[2];
#pragma unroll
            for (int nt2 = 0; nt2 < 2; ++nt2) {
                f32x16 a = {};
                int row = nt2 * 32 + l31;    // K row (per-lane)
#pragma unroll
                for (int ks = 0; ks < 8; ++ks) {
                    short8 kf = *(const short8*)(Kb + row * 256 + SWZ(row, ks * 32 + h2 * 16));
                    a = __builtin_amdgcn_mfma_f32_32x32x16_bf16(kf, qf[ks], a, 0, 0, 0);
                }
                s2[nt2] = a;
            }
            // scale + causal mask (diag tile only); q_local = half*32+l31
            if (kt == qt) {
                int qrow = half * 32 + l31;
#pragma unroll
                for (int nt2 = 0; nt2 < 2; ++nt2)
#pragma unroll
                    for (int r = 0; r < 16; ++r) {
                        int kvr = nt2 * 32 + (r & 3) + 8 * (r >> 2) + 4 * h2;
                        float v = s2[nt2][r] * scale;
                        if (kvr > qrow) v = -1e30f;
                        s2[nt2][r] = v;
                    }
            } else {
#pragma unroll
                for (int nt2 = 0; nt2 < 2; ++nt2)
#pragma unroll
                    for (int r = 0; r < 16; ++r) s2[nt2][r] *= scale;
            }
            // row max: 31 in-lane + cross-half
            float mx = s2[0][0];
#pragma unroll
            for (int nt2 = 0; nt2 < 2; ++nt2)
#pragma unroll
                for (int r = 0; r < 16; ++r) mx = fmaxf(mx, s2[nt2][r]);
            mx = fmaxf(mx, __shfl_xor(mx, 32));
            // defer-max (T13, THR=8 => P <= e^8, bf16/f32-safe): rescale rare
            if (!__all(mx <= m_ + 8.0f)) {
                float mn = fmaxf(m_, mx);
                float alpha = __expf(m_ - mn);
                m_ = mn;
                l_ *= alpha;
#pragma unroll
                for (int r = 0; r < 16; ++r) {
                    float ar = __shfl(alpha, (r & 3) + 8 * (r >> 2) + 4 * h2);
#pragma unroll
                    for (int dblk = 0; dblk < 4; ++dblk) o2[dblk][r] *= ar;
                }
            }
            // p = exp(s - m), sum
            float sum = 0.f;
#pragma unroll
            for (int nt2 = 0; nt2 < 2; ++nt2)
#pragma unroll
                for (int r = 0; r < 16; ++r) {
                    float p = __expf(s2[nt2][r] - m_);
                    s2[nt2][r] = p;
                    sum += p;
                }
            sum += __shfl_xor(sum, 32);
            l_ += sum;
            // pack P -> PV A-frags per 16-kv chunk; lane half-exchange:
            // h2=0 holds chunk rows {0-3,8-11}, h2=1 {4-7,12-15}; A-frag
            // needs k=h2*8+e => swap the middle pairs via shfl_xor(32).
            short8 pa[4];
#pragma unroll
            for (int ch = 0; ch < 4; ++ch) {
                int nt2 = ch >> 1, cc = (ch & 1) * 8;
                unsigned int xa = pkbf(s2[nt2][cc + 0], s2[nt2][cc + 1]);
                unsigned int xb = pkbf(s2[nt2][cc + 2], s2[nt2][cc + 3]);
                unsigned int xc = pkbf(s2[nt2][cc + 4], s2[nt2][cc + 5]);
                unsigned int xd = pkbf(s2[nt2][cc + 6], s2[nt2][cc + 7]);
                unsigned int r1 = (unsigned int)__shfl_xor((int)(h2 ? xa : xc), 32);
                unsigned int r2 = (unsigned int)__shfl_xor((int)(h2 ? xb : xd), 32);
                union { unsigned int u[4]; short8 s8; } uu;
                uu.u[0] = h2 ? r1 : xa;
                uu.u[1] = h2 ? r2 : xb;
                uu.u[2] = h2 ? xc : r1;
                uu.u[3] = h2 ? xd : r2;
                pa[ch] = uu.s8;
            }
            // O += P^T V : 4 d-blocks x 4 kv-chunks
#pragma unroll
            for (int dblk = 0; dblk < 4; ++dblk) {
                int row = dblk * 32 + l31;   // V row (d, per-lane)
                f32x16 acc = o2[dblk];
#pragma unroll
                for (int ch = 0; ch < 4; ++ch) {
                    short8 bv = *(const short8*)(Vb + row * 128 + SWZ(row, ch * 32 + h2 * 16));
                    acc = __builtin_amdgcn_mfma_f32_32x32x16_bf16(pa[ch], bv, acc, 0, 0, 0);
                }
                o2[dblk] = acc;
            }
        }
        __syncthreads();   // before restaging Ks/Vs
    }
    // write O in-place over the Q slice; q = reg-mapped, d = l31
    {
        float rl = 1.0f / l_;
#pragma unroll
        for (int r = 0; r < 16; ++r) {
            int qreg = (r & 3) + 8 * (r >> 2) + 4 * h2;
            float inv = __shfl(rl, qreg);
            int row = qt * 64 + half * 32 + qreg;
#pragma unroll
            for (int dblk = 0; dblk < 4; ++dblk)
                qkv[(size_t)(b * 2048 + row) * 3072 + h * 128 + dblk * 32 + l31] =
                    f2u(o2[dblk][r] * inv);
        }
    }
}

// ---------------------------------------------------------------------------
// Workspace layout (peak 46.1 MiB, proven):
//   [0,         8388608)  WoT   [2048][2048]   live until final GEMM
//   [8388608,  33554432)  QKV   [4096][3072]   q-slice becomes O in-place
//   [33554432, 37748736)  vT    [8][128][2048] written AFTER WTqkv is dead
//   [33554432, 46137344)  WTqkv [3072][2048]   dead after QKV GEMM
// xbf (bf16 copy of x, 16.8 MB) lives in d_out (dead until final GEMM).
extern "C" void kernel_launch(void* const* d_in, const int* in_sizes, int n_in,
                              void* d_out, int out_size, void* d_ws, size_t ws_size,
                              hipStream_t stream) {
    const float* x  = (const float*)d_in[0];   // [2,2048,2048] fp32
    const float* Wq = (const float*)d_in[1];   // [2048,2048]
    const float* Wk = (const float*)d_in[2];   // [2048,512]
    const float* Wv = (const float*)d_in[3];   // [2048,512]
    const float* Wo = (const float*)d_in[4];   // [2048,2048]
    const float* qg = (const float*)d_in[5];   // [128]
    const float* kg = (const float*)d_in[6];   // [128]

    char* ws = (char*)d_ws;
    u16* WoT   = (u16*)(ws);
    u16* QKV   = (u16*)(ws + 8388608);
    u16* vT    = (u16*)(ws + 33554432);
    u16* WTqkv = (u16*)(ws + 33554432);
    u16* xbf   = (u16*)d_out;                  // 16.8 MB of 33.5 MB; dead at GEMM2

    // 0. x->bf16 + all weight transposes, one launch
    prep<<<dim3(6656), 256, 0, stream>>>(x, Wq, Wk, Wv, Wo, xbf, WTqkv, WoT);

    // 1. QKV projection with fused per-head RMSNorm on q/k tiles
    gemm_lds<<<dim3(24, 32), 256, 0, stream>>>(xbf, 2048, WTqkv, QKV, 3072,
                                               nullptr, 0, 4096, 3072, 2048,
                                               qg, kg, 1);

    // 2. V transpose (WTqkv now dead; vT overlays it)
    vtrans<<<dim3(32, 4, 2), 256, 0, stream>>>(QKV, vT);

    // 3. causal GQA flash attention (paired q-tiles, 32x32x16 MFMA,
    //    32 q-rows/wave, lane-local P, half-exchange via shfl_xor(32))
    attn<<<dim3(16, 16, 2), 256, 0, stream>>>(QKV, vT);

    // 4. output projection + residual (C = d_out fp32)
    gemm_lds<<<dim3(16, 32), 256, 0, stream>>>(QKV, 3072, WoT, d_out, 2048,
                                               x, 1, 4096, 2048, 2048,
                                               nullptr, nullptr, 0);
}

// Round 10
// 368.083 us; speedup vs baseline: 1.1286x; 1.1286x over previous
//
#include <hip/hip_runtime.h>

typedef unsigned short u16;
typedef __attribute__((ext_vector_type(8))) short short8;    // 8 x bf16 (4 VGPRs)
typedef __attribute__((ext_vector_type(4))) float f32x4;     // 16x16 MFMA C/D
typedef __attribute__((ext_vector_type(16))) float f32x16;   // 32x32 MFMA C/D

#define DEVI __device__ __forceinline__

DEVI float u2f(u16 u) {
    unsigned int x = ((unsigned int)u) << 16;
    float f; __builtin_memcpy(&f, &x, 4); return f;
}
DEVI u16 f2u(float f) {  // RNE bf16 (finite values)
    unsigned int x; __builtin_memcpy(&x, &f, 4);
    x = (x + 0x7fffu + ((x >> 16) & 1u)) >> 16;
    return (u16)x;
}
DEVI unsigned int fbits(float f) {
    unsigned int x; __builtin_memcpy(&x, &f, 4); return x;
}
// pack two f32 (as truncated bf16) into one u32: [lo | hi<<16]
DEVI unsigned int pkbf(float lo, float hi) {
    return __builtin_amdgcn_perm(fbits(hi), fbits(lo), 0x07060302u);
}
// async global->LDS, 16B per lane; lds base must be wave-uniform (m104/m108)
DEVI void gld16(const u16* g, u16* ldsbase) {
    __builtin_amdgcn_global_load_lds(
        (const __attribute__((address_space(1))) unsigned int*)g,
        (__attribute__((address_space(3))) unsigned int*)ldsbase, 16, 0, 0);
}

// ---------------------------------------------------------------------------
// Prep (one launch): blocks 0..4095 convert x fp32->bf16 (8 floats/thread);
// blocks 4096..6655 transpose the four weight matrices to K-inner bf16.
// grid 6656, block 256.
__global__ __launch_bounds__(256) void prep(
    const float* __restrict__ x,
    const float* __restrict__ Wq, const float* __restrict__ Wk,
    const float* __restrict__ Wv, const float* __restrict__ Wo,
    u16* __restrict__ xbf, u16* __restrict__ WTqkv, u16* __restrict__ WoT)
{
    __shared__ u16 T[64 * 72];
    int id = blockIdx.x;
    const int tid = threadIdx.x;
    if (id < 4096) {
        int g = (id * 256 + tid) * 8;
        float4 a = *(const float4*)&x[g];
        float4 c = *(const float4*)&x[g + 4];
        short8 v;
        v[0]=(short)f2u(a.x); v[1]=(short)f2u(a.y); v[2]=(short)f2u(a.z); v[3]=(short)f2u(a.w);
        v[4]=(short)f2u(c.x); v[5]=(short)f2u(c.y); v[6]=(short)f2u(c.z); v[7]=(short)f2u(c.w);
        *(short8*)&xbf[g] = v;
        return;
    }
    id -= 4096;
    const float* W; u16* WT; int N, bx, by;
    if (id < 1024)      {            W = Wo; WT = WoT;   N = 2048; bx = id & 31; by = id >> 5; }
    else if (id < 2048) { id -= 1024; W = Wq; WT = WTqkv; N = 2048; bx = id & 31; by = id >> 5; }
    else if (id < 2304) { id -= 2048; W = Wk; WT = WTqkv + (size_t)2048 * 2048; N = 512; bx = id & 7; by = id >> 3; }
    else                { id -= 2304; W = Wv; WT = WTqkv + (size_t)2560 * 2048; N = 512; bx = id & 7; by = id >> 3; }
    const int K = 2048;
    const int k0 = by * 64, n0 = bx * 64;
#pragma unroll
    for (int i = 0; i < 2; ++i) {
        int c = tid + i * 256;              // 0..511
        int row = c >> 3, n8 = (c & 7) * 8;
        const float* src = &W[(size_t)(k0 + row) * N + n0 + n8];
#pragma unroll
        for (int j = 0; j < 8; ++j)
            T[(n8 + j) * 72 + row] = f2u(src[j]);
    }
    __syncthreads();
#pragma unroll
    for (int i = 0; i < 2; ++i) {
        int c = tid + i * 256;
        int n = c >> 3, k8 = (c & 7) * 8;
        *(short8*)&WT[(size_t)(n0 + n) * K + k0 + k8] = *(const short8*)&T[n * 72 + k8];
    }
}

// ---------------------------------------------------------------------------
// GEMM: C[M][N] = A[M][K] @ WT[N][K]^T (+ optional fp32 residual).
// m97 structure: unpadded [128][32] LDS tiles, global_load_lds width=16.
// If fuse_norm: N-tiles with n0<2560 get per-head RMSNorm fused in epilogue.
// C written fp32 if c_f32 else bf16.  grid (N/128, M/128), block 256.
__global__ __launch_bounds__(256) void gemm_lds(
    const u16* __restrict__ A, int lda,
    const u16* __restrict__ WT,
    void* __restrict__ C, int ldc, const float* __restrict__ resid, int c_f32,
    int M, int N, int K,
    const float* __restrict__ qg, const float* __restrict__ kg, int fuse_norm)
{
    __shared__ u16 As[128 * 32];
    __shared__ u16 Bs[128 * 32];
    const int tid = threadIdx.x;
    const int lane = tid & 63, w = tid >> 6;
    const int wm = w >> 1, wn = w & 1;
    const int l15 = lane & 15, quad = lane >> 4;
    const int r4 = lane >> 2, c4 = (lane & 3) * 8;  // DMA: lane->row/col-8
    const int m0 = blockIdx.y * 128, n0 = blockIdx.x * 128;

    f32x4 acc[4][4] = {};
    for (int k0 = 0; k0 < K; k0 += 32) {
#pragma unroll
        for (int j = 0; j < 2; ++j) {
            int row = w * 32 + j * 16;
            gld16(&WT[(size_t)(n0 + row + r4) * K + k0 + c4], &Bs[row * 32]);
            gld16(&A [(size_t)(m0 + row + r4) * lda + k0 + c4], &As[row * 32]);
        }
        __syncthreads();
        short8 a[4], b[4];
#pragma unroll
        for (int mt = 0; mt < 4; ++mt)
            a[mt] = *(const short8*)&As[(wm * 64 + mt * 16 + l15) * 32 + quad * 8];
#pragma unroll
        for (int nt = 0; nt < 4; ++nt)
            b[nt] = *(const short8*)&Bs[(wn * 64 + nt * 16 + l15) * 32 + quad * 8];
#pragma unroll
        for (int mt = 0; mt < 4; ++mt)
#pragma unroll
            for (int nt = 0; nt < 4; ++nt)
                acc[mt][nt] = __builtin_amdgcn_mfma_f32_16x16x32_bf16(a[mt], b[nt], acc[mt][nt], 0, 0, 0);
        __syncthreads();
    }

    if (fuse_norm && n0 < 2560) {
        const float* gamma = (n0 < 2048) ? qg : kg;
        float* red = (float*)As;             // 256 floats, As is dead
#pragma unroll
        for (int mt = 0; mt < 4; ++mt)
#pragma unroll
            for (int r = 0; r < 4; ++r) {
                float p = 0.f;
#pragma unroll
                for (int nt = 0; nt < 4; ++nt) p += acc[mt][nt][r] * acc[mt][nt][r];
#pragma unroll
                for (int msk = 1; msk < 16; msk <<= 1) p += __shfl_xor(p, msk);
                if (l15 == 0)
                    red[(wm * 64 + mt * 16 + quad * 4 + r) * 2 + wn] = p;
            }
        __syncthreads();
        float gv[4];
#pragma unroll
        for (int nt = 0; nt < 4; ++nt) gv[nt] = gamma[wn * 64 + nt * 16 + l15];
#pragma unroll
        for (int mt = 0; mt < 4; ++mt)
#pragma unroll
            for (int r = 0; r < 4; ++r) {
                int rl = wm * 64 + mt * 16 + quad * 4 + r;
                float m2 = red[rl * 2] + red[rl * 2 + 1];
                float sc = rsqrtf(m2 * (1.0f / 128.0f) + 1e-8f);
#pragma unroll
                for (int nt = 0; nt < 4; ++nt) acc[mt][nt][r] *= sc * gv[nt];
            }
    }

#pragma unroll
    for (int mt = 0; mt < 4; ++mt) {
#pragma unroll
        for (int r = 0; r < 4; ++r) {
            int row = m0 + wm * 64 + mt * 16 + quad * 4 + r;
#pragma unroll
            for (int nt = 0; nt < 4; ++nt) {
                int col = n0 + wn * 64 + nt * 16 + l15;
                float v = acc[mt][nt][r];
                if (resid) v += resid[(size_t)row * ldc + col];
                if (c_f32) ((float*)C)[(size_t)row * ldc + col] = v;
                else       ((u16*)C)[(size_t)row * ldc + col] = f2u(v);
            }
        }
    }
}

// ---------------------------------------------------------------------------
// V transpose: vT[(b*4+kvh)*128 + d][s] = qkv[(b*2048+s)][2560 + kvh*128 + d]
// grid (32, 4, 2), block 256.  (bf16)
__global__ __launch_bounds__(256) void vtrans(
    const u16* __restrict__ qkv, u16* __restrict__ vT)
{
    __shared__ u16 T[128 * 72];
    const int tid = threadIdx.x;
    const int t0 = blockIdx.x * 64;
    const int kvh = blockIdx.y, b = blockIdx.z;
#pragma unroll
    for (int i = 0; i < 4; ++i) {
        int c = tid + i * 256;                // 0..1023
        int tl = c >> 4, d8 = (c & 15) * 8;
        short8 v = *(const short8*)&qkv[(size_t)(b * 2048 + t0 + tl) * 3072 + 2560 + kvh * 128 + d8];
#pragma unroll
        for (int j = 0; j < 8; ++j)
            T[(d8 + j) * 72 + tl] = (u16)v[j];
    }
    __syncthreads();
#pragma unroll
    for (int i = 0; i < 4; ++i) {
        int c = tid + i * 256;
        int d = c >> 3, t8 = (c & 7) * 8;
        *(short8*)&vT[((size_t)(b * 4 + kvh) * 128 + d) * 2048 + t0 + t8] =
            *(const short8*)&T[d * 72 + t8];
    }
}

// ---------------------------------------------------------------------------
// Flash attention, causal, GQA, paired q-tiles (qt, 31-qt), 4 waves/block,
// 32x32x16 MFMA (layouts HW-verified by r9's pass).  ROUND 10: r9 with the
// VGPR budget fixed (r9: 156 VGPR -> 1 block/CU -> latency-bound 140us;
// empirical law r0/r4/r5/r9: VGPR<=128 <=> 2 blocks/CU):
//  - S processed in 32-kv chunks: one f32x16 live (not two), two online
//    softmax updates per kv-iter (exact); fully-masked diag chunk skipped.
//  - Q in LDS (32KB region, staged once) read per chunk, not 32 VGPRs.
// Budget: o2 64 + s 16 + pa 8 + temps ~28 = ~116 VGPR.
// LDS model (explains r0==r6==r8==107us): time ~= total LDS ops x cost;
// this structure: reads 0.75x r0, shuffles 0.1x r0 per CU.
// grid (16, 16, 2), block 256, LDS 64KB (K 16K + V 16K + Q 32K, swizzled).
#define SWZ(row, coloff) ((coloff) ^ (((row) & 7) << 4))
__global__ __launch_bounds__(256) void attn(
    u16* __restrict__ qkv, const u16* __restrict__ vT)
{
    __shared__ u16 lds[32768];               // 65,536 B
    char* const Kb = (char*)lds;             // K: [64]x256B    [0,16K)
    char* const Vb = (char*)lds + 16384;     // V: [128]x128B   [16K,32K)
    char* const Qb = (char*)lds + 32768;     // Q: [128]x256B   [32K,64K)

    const int tid = threadIdx.x, lane = tid & 63, w = tid >> 6;
    const int t = w >> 1, half = w & 1;      // tile owner, q-half (32 rows)
    const int l31 = lane & 31, h2 = lane >> 5;
    const int h = blockIdx.y, b = blockIdx.z;
    const int kvh = h >> 2;
    const int qts0 = (int)blockIdx.x, qts1 = 31 - (int)blockIdx.x;
    const int qt = t ? qts1 : qts0;          // this wave's q-tile
    const float scale = 0.08838834764831845f;

    // prologue: stage both Q tiles into Qb (row = tile*64 + in-tile row)
#pragma unroll
    for (int i = 0; i < 8; ++i) {
        int c = tid + i * 256;               // 0..2047
        int r = c >> 4, co = (c & 15) * 16;
        int qtile = (r >> 6) ? qts1 : qts0;
        short8 v = *(const short8*)&qkv[(size_t)(b * 2048 + qtile * 64 + (r & 63)) * 3072 + h * 128 + (c & 15) * 8];
        *(short8*)(Qb + r * 256 + SWZ(r, co)) = v;
    }
    const int myqrow = t * 64 + half * 32 + l31;   // Qb row for this lane

    f32x16 o2[4] = {};                       // O: 4 d-blocks of 32
    float m_ = -1e30f, l_ = 0.f;

    for (int kt = 0; kt <= qts1; ++kt) {
        const int kv0 = kt * 64;
        // stage K,V swizzled (256 threads: 4+4 b128 chunks/thread)
#pragma unroll
        for (int i = 0; i < 4; ++i) {
            int c = tid + i * 256;           // 0..1023
            int r = c >> 4, co = (c & 15) * 16;
            short8 v = *(const short8*)&qkv[(size_t)(b * 2048 + kv0 + r) * 3072 + 2048 + kvh * 128 + (c & 15) * 8];
            *(short8*)(Kb + r * 256 + SWZ(r, co)) = v;
        }
#pragma unroll
        for (int i = 0; i < 4; ++i) {
            int c = tid + i * 256;
            int d = c >> 3, co = (c & 7) * 16;
            short8 v = *(const short8*)&vT[((size_t)(b * 4 + kvh) * 128 + d) * 2048 + kv0 + (c & 7) * 8];
            *(short8*)(Vb + d * 128 + SWZ(d, co)) = v;
        }
        __syncthreads();   // also orders the one-time Q staging (iter 0)

        if (kt <= qt) {                      // wave-uniform: tile active
#pragma unroll
            for (int nt2 = 0; nt2 < 2; ++nt2) {
                // diag tile, lower q-half: chunk 1 (kv 32..63) fully masked
                if (kt == qt && half == 0 && nt2 == 1) continue;  // wave-uniform
                // S chunk = K[kv0+nt2*32 ..] Q^T (32x32)
                f32x16 s = {};
                int krow = nt2 * 32 + l31;
#pragma unroll
                for (int ks = 0; ks < 8; ++ks) {
                    short8 kf = *(const short8*)(Kb + krow * 256 + SWZ(krow, ks * 32 + h2 * 16));
                    short8 qf = *(const short8*)(Qb + myqrow * 256 + SWZ(myqrow, ks * 32 + h2 * 16));
                    s = __builtin_amdgcn_mfma_f32_32x32x16_bf16(kf, qf, s, 0, 0, 0);
                }
                // scale + causal mask (diag tile only); q_local = half*32+l31
                if (kt == qt) {
                    int qrow = half * 32 + l31;
#pragma unroll
                    for (int r = 0; r < 16; ++r) {
                        int kvr = nt2 * 32 + (r & 3) + 8 * (r >> 2) + 4 * h2;
                        float v = s[r] * scale;
                        if (kvr > qrow) v = -1e30f;
                        s[r] = v;
                    }
                } else {
#pragma unroll
                    for (int r = 0; r < 16; ++r) s[r] *= scale;
                }
                // chunk max (15 in-lane + cross-half)
                float mx = s[0];
#pragma unroll
                for (int r = 1; r < 16; ++r) mx = fmaxf(mx, s[r]);
                mx = fmaxf(mx, __shfl_xor(mx, 32));
                // defer-max (T13, THR=8 => P <= e^8): rescale rarely
                if (!__all(mx <= m_ + 8.0f)) {
                    float mn = fmaxf(m_, mx);
                    float alpha = __expf(m_ - mn);
                    m_ = mn;
                    l_ *= alpha;
#pragma unroll
                    for (int r = 0; r < 16; ++r) {
                        float ar = __shfl(alpha, (r & 3) + 8 * (r >> 2) + 4 * h2);
#pragma unroll
                        for (int dblk = 0; dblk < 4; ++dblk) o2[dblk][r] *= ar;
                    }
                }
                // p = exp(s - m), sum
                float sum = 0.f;
#pragma unroll
                for (int r = 0; r < 16; ++r) {
                    float p = __expf(s[r] - m_);
                    s[r] = p;
                    sum += p;
                }
                sum += __shfl_xor(sum, 32);
                l_ += sum;
                // pack P -> 2 PV A-frags (16-kv sub-chunks); half-exchange:
                // h2=0 holds rows {0-3,8-11}, h2=1 {4-7,12-15} of the chunk;
                // A-frag needs k=h2*8+e => swap middle pairs via shfl_xor(32).
                short8 pa[2];
#pragma unroll
                for (int cc = 0; cc < 2; ++cc) {
                    unsigned int xa = pkbf(s[cc * 8 + 0], s[cc * 8 + 1]);
                    unsigned int xb = pkbf(s[cc * 8 + 2], s[cc * 8 + 3]);
                    unsigned int xc = pkbf(s[cc * 8 + 4], s[cc * 8 + 5]);
                    unsigned int xd = pkbf(s[cc * 8 + 6], s[cc * 8 + 7]);
                    unsigned int r1 = (unsigned int)__shfl_xor((int)(h2 ? xa : xc), 32);
                    unsigned int r2 = (unsigned int)__shfl_xor((int)(h2 ? xb : xd), 32);
                    union { unsigned int u[4]; short8 s8; } uu;
                    uu.u[0] = h2 ? r1 : xa;
                    uu.u[1] = h2 ? r2 : xb;
                    uu.u[2] = h2 ? xc : r1;
                    uu.u[3] = h2 ? xd : r2;
                    pa[cc] = uu.s8;
                }
                // O += P^T V for this 32-kv chunk (4 d-blocks x 2 sub-chunks)
#pragma unroll
                for (int dblk = 0; dblk < 4; ++dblk) {
                    int vrow = dblk * 32 + l31;  // V row (d, per-lane)
                    f32x16 acc = o2[dblk];
                    short8 bv0 = *(const short8*)(Vb + vrow * 128 + SWZ(vrow, nt2 * 64 + h2 * 16));
                    acc = __builtin_amdgcn_mfma_f32_32x32x16_bf16(pa[0], bv0, acc, 0, 0, 0);
                    short8 bv1 = *(const short8*)(Vb + vrow * 128 + SWZ(vrow, nt2 * 64 + 32 + h2 * 16));
                    acc = __builtin_amdgcn_mfma_f32_32x32x16_bf16(pa[1], bv1, acc, 0, 0, 0);
                    o2[dblk] = acc;
                }
            }
        }
        __syncthreads();   // before restaging Ks/Vs
    }
    // write O in-place over the Q slice; q = reg-mapped, d = l31
    {
        float rl = 1.0f / l_;
#pragma unroll
        for (int r = 0; r < 16; ++r) {
            int qreg = (r & 3) + 8 * (r >> 2) + 4 * h2;
            float inv = __shfl(rl, qreg);
            int row = qt * 64 + half * 32 + qreg;
#pragma unroll
            for (int dblk = 0; dblk < 4; ++dblk)
                qkv[(size_t)(b * 2048 + row) * 3072 + h * 128 + dblk * 32 + l31] =
                    f2u(o2[dblk][r] * inv);
        }
    }
}

// ---------------------------------------------------------------------------
// Workspace layout (peak 46.1 MiB, proven):
//   [0,         8388608)  WoT   [2048][2048]   live until final GEMM
//   [8388608,  33554432)  QKV   [4096][3072]   q-slice becomes O in-place
//   [33554432, 37748736)  vT    [8][128][2048] written AFTER WTqkv is dead
//   [33554432, 46137344)  WTqkv [3072][2048]   dead after QKV GEMM
// xbf (bf16 copy of x, 16.8 MB) lives in d_out (dead until final GEMM).
extern "C" void kernel_launch(void* const* d_in, const int* in_sizes, int n_in,
                              void* d_out, int out_size, void* d_ws, size_t ws_size,
                              hipStream_t stream) {
    const float* x  = (const float*)d_in[0];   // [2,2048,2048] fp32
    const float* Wq = (const float*)d_in[1];   // [2048,2048]
    const float* Wk = (const float*)d_in[2];   // [2048,512]
    const float* Wv = (const float*)d_in[3];   // [2048,512]
    const float* Wo = (const float*)d_in[4];   // [2048,2048]
    const float* qg = (const float*)d_in[5];   // [128]
    const float* kg = (const float*)d_in[6];   // [128]

    char* ws = (char*)d_ws;
    u16* WoT   = (u16*)(ws);
    u16* QKV   = (u16*)(ws + 8388608);
    u16* vT    = (u16*)(ws + 33554432);
    u16* WTqkv = (u16*)(ws + 33554432);
    u16* xbf   = (u16*)d_out;                  // 16.8 MB of 33.5 MB; dead at GEMM2

    // 0. x->bf16 + all weight transposes, one launch
    prep<<<dim3(6656), 256, 0, stream>>>(x, Wq, Wk, Wv, Wo, xbf, WTqkv, WoT);

    // 1. QKV projection with fused per-head RMSNorm on q/k tiles
    gemm_lds<<<dim3(24, 32), 256, 0, stream>>>(xbf, 2048, WTqkv, QKV, 3072,
                                               nullptr, 0, 4096, 3072, 2048,
                                               qg, kg, 1);

    // 2. V transpose (WTqkv now dead; vT overlays it)
    vtrans<<<dim3(32, 4, 2), 256, 0, stream>>>(QKV, vT);

    // 3. causal GQA flash attention (paired q-tiles, 32x32x16 MFMA,
    //    chunked softmax + Q-in-LDS: VGPR under the 128 residency cliff)
    attn<<<dim3(16, 16, 2), 256, 0, stream>>>(QKV, vT);

    // 4. output projection + residual (C = d_out fp32)
    gemm_lds<<<dim3(16, 32), 256, 0, stream>>>(QKV, 3072, WoT, d_out, 2048,
                                               x, 1, 4096, 2048, 2048,
                                               nullptr, nullptr, 0);
}